// Round 5
// baseline (183.223 us; speedup 1.0000x reference)
//
#include <hip/hip_runtime.h>
#include <stdint.h>

// OctonionLinear == GEMM: out[b, i*8+k] = sum_{j,p} x[b, j*8+p] * W[i,j,p,k] + bias[i,k]
// M=512, N=4096, K=4096, fp32 in/out, bf16 MFMA.
// R5: register-direct GEMM — NO LDS AT ALL. R1/R3/R4 (three different
//   LDS-staged K-loop structures) all plateaued at 54-59us with MfmaUtil
//   ~11.5%: the compiler serializes any global_load_lds -> ds_read pair with
//   its own vmcnt(0) (can't disambiguate the LDS hazard), so no source-level
//   pipeline takes effect. Here each lane loads its MFMA fragments directly
//   from global into VGPRs (wave touches 16 fully-consumed 64B lines per
//   load), depth-2 software pipeline, fully unrolled K-loop with immediate
//   address offsets -> pure load<->MFMA interleave the compiler schedules
//   with fine-grained per-register vmcnt (the AITER pattern in HIP).
//   L2-side refetch ~384MB ≈ 15us floor; MFMA floor ~2.1us.
// prep unchanged from R3; KSPLIT=4 + atomic epilogue unchanged.

#define M_DIM 512
#define N_DIM 4096
#define K_DIM 4096
#define KSPLIT 4
#define NIT ((K_DIM / KSPLIT) / 32)  // 32

typedef __bf16 bf16x8 __attribute__((ext_vector_type(8)));
typedef float f32x4 __attribute__((ext_vector_type(4)));

__device__ inline unsigned short f2bf(float f) {
  union { float f; unsigned int u; } v;
  v.f = f;
  unsigned int u = v.u;
  unsigned int r = (u + 0x7fffu + ((u >> 16) & 1u)) >> 16;  // RNE
  return (unsigned short)r;
}

// blocks [0,4096): W transpose+convert -> bt[nn][kk], coalesced 16KB chunks.
// blocks [4096,5120): x convert -> abf, 8 el/thread.
// blocks [5120,7168): out = bias broadcast, 4 el/thread.
__global__ __launch_bounds__(256) void prep_kernel(
    const float* __restrict__ x, const float* __restrict__ w,
    const float* __restrict__ bias, unsigned short* __restrict__ abf,
    unsigned short* __restrict__ bt, float* __restrict__ out) {
  const int bid = blockIdx.x;
  const int t = threadIdx.x;
  if (bid < 4096) {
    __shared__ __align__(16) unsigned short lT[8][512];  // [k][j'*8+p], 8KB
    const int i = bid >> 3;
    const int jg = bid & 7;
    const float4* src =
        (const float4*)(w + (size_t)i * 32768 + jg * 4096 + t * 16);
    float4 v0 = src[0], v1 = src[1], v2 = src[2], v3 = src[3];
    const int jp = (t >> 2) * 8 + (t & 3) * 2;  // j'*8 + p0 (even)
    const float* lo = (const float*)&v0;  // k=0..3, p0   (v1: k=4..7)
    const float* hi = (const float*)&v2;  // k=0..3, p0+1 (v3: k=4..7)
#pragma unroll
    for (int k = 0; k < 4; ++k) {
      unsigned int pk =
          (unsigned int)f2bf(lo[k]) | ((unsigned int)f2bf(hi[k]) << 16);
      *(unsigned int*)&lT[k][jp] = pk;
    }
    lo = (const float*)&v1;
    hi = (const float*)&v3;
#pragma unroll
    for (int k = 0; k < 4; ++k) {
      unsigned int pk =
          (unsigned int)f2bf(lo[k]) | ((unsigned int)f2bf(hi[k]) << 16);
      *(unsigned int*)&lT[k + 4][jp] = pk;
    }
    __syncthreads();
    const int r = t >> 5, c = t & 31;  // 32B/thread, 1KB contiguous runs
    const uint4* s = (const uint4*)&lT[r][c * 16];
    uint4* d = (uint4*)(bt + (size_t)(i * 8 + r) * K_DIM + jg * 512 + c * 16);
    d[0] = s[0];
    d[1] = s[1];
  } else if (bid < 5120) {
    int g = (bid - 4096) * 256 + t;  // [0, 262144); 8 elements each
    const float4* xi = (const float4*)x;
    float4 a = xi[g * 2];
    float4 b = xi[g * 2 + 1];
    __attribute__((aligned(16))) unsigned short o[8] = {
        f2bf(a.x), f2bf(a.y), f2bf(a.z), f2bf(a.w),
        f2bf(b.x), f2bf(b.y), f2bf(b.z), f2bf(b.w)};
    *(uint4*)(abf + (size_t)g * 8) = *(const uint4*)o;
  } else {
    int g = (bid - 5120) * 256 + t;  // [0, 524288); 4 elements each
    int el = g * 4;
    int col = el & (N_DIM - 1);
    *(float4*)(out + el) = *(const float4*)(bias + col);
  }
}

__global__ __launch_bounds__(256, 2) void gemm_kernel(
    const unsigned short* __restrict__ A, const unsigned short* __restrict__ Bt,
    float* __restrict__ out) {
  const int t = threadIdx.x;
  const int n0 = blockIdx.x * 128;
  const int m0 = blockIdx.y * 128;
  const int kc0 = blockIdx.z * (K_DIM / KSPLIT);
  const int w = t >> 6;
  const int lane = t & 63;
  const int wr = w >> 1;     // wave row -> 64 rows of M
  const int wc = w & 1;      // wave col -> 64 cols of N
  const int lrow = lane & 15;
  const int kb = lane >> 4;  // k-block 0..3 (8 bf16 each)

  // Fragment base pointers: lane's 16B segment for each 16-row subtile.
  // Wave's 64 lanes touch 16 distinct fully-consumed 64B lines per load.
  const unsigned short* pA[4];
  const unsigned short* pB[4];
#pragma unroll
  for (int mt = 0; mt < 4; ++mt)
    pA[mt] = A + (size_t)(m0 + wr * 64 + mt * 16 + lrow) * K_DIM + kc0 + kb * 8;
#pragma unroll
  for (int nt = 0; nt < 4; ++nt)
    pB[nt] =
        Bt + (size_t)(n0 + wc * 64 + nt * 16 + lrow) * K_DIM + kc0 + kb * 8;

  f32x4 acc[4][4] = {};
  bf16x8 fA[2][4], fB[2][4];

#pragma unroll
  for (int mt = 0; mt < 4; ++mt) {
    fA[0][mt] = *(const bf16x8*)(pA[mt]);
    fB[0][mt] = *(const bf16x8*)(pB[mt]);
  }

#pragma unroll
  for (int it = 0; it < NIT; ++it) {
    const int cur = it & 1, nxt = cur ^ 1;
    if (it + 1 < NIT) {
      // prefetch next iter's fragments; k advance = 32 el = 64B imm offset
#pragma unroll
      for (int mt = 0; mt < 4; ++mt) {
        fA[nxt][mt] = *(const bf16x8*)(pA[mt] + (it + 1) * 32);
        fB[nxt][mt] = *(const bf16x8*)(pB[mt] + (it + 1) * 32);
      }
    }
#pragma unroll
    for (int mt = 0; mt < 4; ++mt)
#pragma unroll
      for (int nt = 0; nt < 4; ++nt)
        acc[mt][nt] = __builtin_amdgcn_mfma_f32_16x16x32_bf16(
            fA[cur][mt], fB[cur][nt], acc[mt][nt], 0, 0, 0);
  }

  // C/D layout (verified m89/m91): col = lane&15, row = (lane>>4)*4 + reg
#pragma unroll
  for (int mt = 0; mt < 4; ++mt) {
    const int gmb = m0 + wr * 64 + mt * 16 + kb * 4;
#pragma unroll
    for (int nt = 0; nt < 4; ++nt) {
      const int gn = n0 + wc * 64 + nt * 16 + lrow;
#pragma unroll
      for (int r = 0; r < 4; ++r)
        atomicAdd(out + (size_t)(gmb + r) * N_DIM + gn, acc[mt][nt][r]);
    }
  }
}

extern "C" void kernel_launch(void* const* d_in, const int* in_sizes, int n_in,
                              void* d_out, int out_size, void* d_ws,
                              size_t ws_size, hipStream_t stream) {
  const float* x = (const float*)d_in[0];     // [512, 4096]
  const float* w = (const float*)d_in[1];     // [512, 512, 8, 8]
  const float* bias = (const float*)d_in[2];  // [512, 8]
  float* out = (float*)d_out;                 // [512, 4096]

  unsigned short* abf = (unsigned short*)d_ws;       // 4 MB bf16 A
  unsigned short* bt = abf + (size_t)M_DIM * K_DIM;  // 32 MB bf16 B^T

  prep_kernel<<<7168, 256, 0, stream>>>(x, w, bias, abf, bt, out);

  dim3 grid(N_DIM / 128, M_DIM / 128, KSPLIT);  // 32 x 4 x 4 = 512 blocks
  gemm_kernel<<<grid, 256, 0, stream>>>(abf, bt, out);
}

// Round 6
// 154.673 us; speedup vs baseline: 1.1846x; 1.1846x over previous
//
#include <hip/hip_runtime.h>
#include <stdint.h>

// OctonionLinear == GEMM: out[b, i*8+k] = sum_{j,p} x[b, j*8+p] * W[i,j,p,k] + bias[i,k]
// M=512, N=4096, K=4096, fp32 in/out, bf16 MFMA.
// R6: occupancy play. R1/R3/R4 (three K-loop structures at 4 waves/block,
//   512 blocks) all sat at 54-59us, occupancy ~17%, per-block-iter wall
//   ~4000cyc vs ~500cyc work — latency-bound with too few waves. R5 showed
//   register-direct is worse (compiler can't hold the pipeline, VALUBusy 2%).
//   This round: tile 128Mx64N, 512 threads = 8 waves (each 32x32, acc=16
//   VGPR), grid 64x4x4 = 1024 blocks = 4 blocks/CU; launch_bounds(512,6)
//   -> 3-4 blocks resident = 24-32 waves/CU (vs ~6). Barrier drains overlap
//   across independent blocks. KSPLIT stays 4 (R2: extra ksplit costs
//   ~1us/M-atomics). LDS 24KB/block dbuf.
// prep unchanged from R3.

#define M_DIM 512
#define N_DIM 4096
#define K_DIM 4096
#define KSPLIT 4
#define NIT ((K_DIM / KSPLIT) / 32)  // 32

typedef __bf16 bf16x8 __attribute__((ext_vector_type(8)));
typedef float f32x4 __attribute__((ext_vector_type(4)));

__device__ inline unsigned short f2bf(float f) {
  union { float f; unsigned int u; } v;
  v.f = f;
  unsigned int u = v.u;
  unsigned int r = (u + 0x7fffu + ((u >> 16) & 1u)) >> 16;  // RNE
  return (unsigned short)r;
}

// blocks [0,4096): W transpose+convert -> bt[nn][kk], coalesced 16KB chunks.
// blocks [4096,5120): x convert -> abf, 8 el/thread.
// blocks [5120,7168): out = bias broadcast, 4 el/thread.
__global__ __launch_bounds__(256) void prep_kernel(
    const float* __restrict__ x, const float* __restrict__ w,
    const float* __restrict__ bias, unsigned short* __restrict__ abf,
    unsigned short* __restrict__ bt, float* __restrict__ out) {
  const int bid = blockIdx.x;
  const int t = threadIdx.x;
  if (bid < 4096) {
    __shared__ __align__(16) unsigned short lT[8][512];  // [k][j'*8+p], 8KB
    const int i = bid >> 3;
    const int jg = bid & 7;
    const float4* src =
        (const float4*)(w + (size_t)i * 32768 + jg * 4096 + t * 16);
    float4 v0 = src[0], v1 = src[1], v2 = src[2], v3 = src[3];
    const int jp = (t >> 2) * 8 + (t & 3) * 2;  // j'*8 + p0 (even)
    const float* lo = (const float*)&v0;  // k=0..3, p0   (v1: k=4..7)
    const float* hi = (const float*)&v2;  // k=0..3, p0+1 (v3: k=4..7)
#pragma unroll
    for (int k = 0; k < 4; ++k) {
      unsigned int pk =
          (unsigned int)f2bf(lo[k]) | ((unsigned int)f2bf(hi[k]) << 16);
      *(unsigned int*)&lT[k][jp] = pk;
    }
    lo = (const float*)&v1;
    hi = (const float*)&v3;
#pragma unroll
    for (int k = 0; k < 4; ++k) {
      unsigned int pk =
          (unsigned int)f2bf(lo[k]) | ((unsigned int)f2bf(hi[k]) << 16);
      *(unsigned int*)&lT[k + 4][jp] = pk;
    }
    __syncthreads();
    const int r = t >> 5, c = t & 31;  // 32B/thread, 1KB contiguous runs
    const uint4* s = (const uint4*)&lT[r][c * 16];
    uint4* d = (uint4*)(bt + (size_t)(i * 8 + r) * K_DIM + jg * 512 + c * 16);
    d[0] = s[0];
    d[1] = s[1];
  } else if (bid < 5120) {
    int g = (bid - 4096) * 256 + t;  // [0, 262144); 8 elements each
    const float4* xi = (const float4*)x;
    float4 a = xi[g * 2];
    float4 b = xi[g * 2 + 1];
    __attribute__((aligned(16))) unsigned short o[8] = {
        f2bf(a.x), f2bf(a.y), f2bf(a.z), f2bf(a.w),
        f2bf(b.x), f2bf(b.y), f2bf(b.z), f2bf(b.w)};
    *(uint4*)(abf + (size_t)g * 8) = *(const uint4*)o;
  } else {
    int g = (bid - 5120) * 256 + t;  // [0, 524288); 4 elements each
    int el = g * 4;
    int col = el & (N_DIM - 1);
    *(float4*)(out + el) = *(const float4*)(bias + col);
  }
}

__device__ inline void gld16(const void* g, void* l) {
  __builtin_amdgcn_global_load_lds(
      (const __attribute__((address_space(1))) unsigned int*)g,
      (__attribute__((address_space(3))) unsigned int*)l, 16, 0, 0);
}

// Tile: 128 M x 64 N, BK=32. LDS buf = A 128x32 (8KB) + B 64x32 (4KB).
// 8 waves: wr = w>>1 (32 M-rows), wc = w&1 (32 N-cols), each 2x2 mfma16.
__global__ __launch_bounds__(512, 6) void gemm_kernel(
    const unsigned short* __restrict__ A, const unsigned short* __restrict__ Bt,
    float* __restrict__ out) {
  __shared__ __align__(16) char lds[2][12 * 1024];  // dbuf, 24KB total
  const int t = threadIdx.x;
  const int n0 = blockIdx.x * 64;
  const int m0 = blockIdx.y * 128;
  const int kc0 = blockIdx.z * (K_DIM / KSPLIT);
  const int w = t >> 6;
  const int lane = t & 63;
  const int wr = w >> 1;     // 0..3 -> 32 M-rows each
  const int wc = w & 1;      // 0..1 -> 32 N-cols each
  const int lrow = lane & 15;
  const int kb = lane >> 4;  // k-block 0..3 (8 bf16 each)

  f32x4 acc[2][2] = {};

  // staging: A 512 segs (1/thread): row t>>2, col (t&3)*8 -> lds + t*16
  //          B 256 segs (threads<256): row t>>2, col (t&3)*8 -> +8KB + t*16
  const size_t aOff = (size_t)(m0 + (t >> 2)) * K_DIM + kc0 + (t & 3) * 8;
  const size_t bOff = (size_t)(n0 + (t >> 2)) * K_DIM + kc0 + (t & 3) * 8;

  auto issue = [&](int it) {
    char* buf = lds[it & 1];
    gld16(A + aOff + it * 32, buf + t * 16);
    if (t < 256) gld16(Bt + bOff + it * 32, buf + 8192 + t * 16);
  };

  issue(0);
  for (int it = 0; it < NIT; ++it) {
    __syncthreads();  // prior ds_reads done; prefetch (issued last iter) drained
    if (it + 1 < NIT) issue(it + 1);
    const unsigned short* cA = (const unsigned short*)lds[it & 1];
    const unsigned short* cB = cA + 4096;  // +8KB

    bf16x8 af[2], bfr[2];
#pragma unroll
    for (int mt = 0; mt < 2; ++mt)
      af[mt] = *(const bf16x8*)(cA + (wr * 32 + mt * 16 + lrow) * 32 + kb * 8);
#pragma unroll
    for (int nt = 0; nt < 2; ++nt)
      bfr[nt] = *(const bf16x8*)(cB + (wc * 32 + nt * 16 + lrow) * 32 + kb * 8);
#pragma unroll
    for (int mt = 0; mt < 2; ++mt)
#pragma unroll
      for (int nt = 0; nt < 2; ++nt)
        acc[mt][nt] = __builtin_amdgcn_mfma_f32_16x16x32_bf16(
            af[mt], bfr[nt], acc[mt][nt], 0, 0, 0);
  }

  // C/D layout (verified m89/m91): col = lane&15, row = (lane>>4)*4 + reg
#pragma unroll
  for (int mt = 0; mt < 2; ++mt) {
    const int gmb = m0 + wr * 32 + mt * 16 + kb * 4;
#pragma unroll
    for (int nt = 0; nt < 2; ++nt) {
      const int gn = n0 + wc * 32 + nt * 16 + lrow;
#pragma unroll
      for (int r = 0; r < 4; ++r)
        atomicAdd(out + (size_t)(gmb + r) * N_DIM + gn, acc[mt][nt][r]);
    }
  }
}

extern "C" void kernel_launch(void* const* d_in, const int* in_sizes, int n_in,
                              void* d_out, int out_size, void* d_ws,
                              size_t ws_size, hipStream_t stream) {
  const float* x = (const float*)d_in[0];     // [512, 4096]
  const float* w = (const float*)d_in[1];     // [512, 512, 8, 8]
  const float* bias = (const float*)d_in[2];  // [512, 8]
  float* out = (float*)d_out;                 // [512, 4096]

  unsigned short* abf = (unsigned short*)d_ws;       // 4 MB bf16 A
  unsigned short* bt = abf + (size_t)M_DIM * K_DIM;  // 32 MB bf16 B^T

  prep_kernel<<<7168, 256, 0, stream>>>(x, w, bias, abf, bt, out);

  dim3 grid(N_DIM / 64, M_DIM / 128, KSPLIT);  // 64 x 4 x 4 = 1024 blocks
  gemm_kernel<<<grid, 512, 0, stream>>>(abf, bt, out);
}

// Round 7
// 138.965 us; speedup vs baseline: 1.3185x; 1.1130x over previous
//
#include <hip/hip_runtime.h>
#include <stdint.h>

// OctonionLinear == GEMM: out[b, i*8+k] = sum_{j,p} x[b, j*8+p] * W[i,j,p,k] + bias[i,k]
// M=512, N=4096, K=4096, fp32 in/out, bf16 MFMA.
// R7: two independent fixes.
//  (1) K-loop: 512-thread 128x128 tile, 8 waves of 64x32 (4x2 mfma16).
//      R6 proved occupancy alone is useless (17%->62%, dur identical) and its
//      2x2 wave-tiles were LDS-pipe-bound (1 b128-read/MFMA + 4.2M conflict
//      cyc). This shape gives 16 waves/CU AND 0.75 reads/MFMA.
//  (2) Epilogue: KSPLIT=4 partials to ws (plain stores) + reduce+bias kernel.
//      R2 showed atomics cost ~1.9us/M (write-through RMW ~2TB/s): ~16us of
//      the 54. Fallback to atomic path if ws_size < 68MB (runtime-constant).
// prep: W-transpose + x-convert; bias-init only in atomic fallback.

#define M_DIM 512
#define N_DIM 4096
#define K_DIM 4096
#define KSPLIT 4
#define NIT ((K_DIM / KSPLIT) / 32)            // 32
#define PART_ELEMS (M_DIM * N_DIM)             // 2097152 floats per z-slice

typedef __bf16 bf16x8 __attribute__((ext_vector_type(8)));
typedef float f32x4 __attribute__((ext_vector_type(4)));

__device__ inline unsigned short f2bf(float f) {
  union { float f; unsigned int u; } v;
  v.f = f;
  unsigned int u = v.u;
  unsigned int r = (u + 0x7fffu + ((u >> 16) & 1u)) >> 16;  // RNE
  return (unsigned short)r;
}

// blocks [0,4096): W transpose+convert -> bt[nn][kk], coalesced 16KB chunks.
// blocks [4096,5120): x convert -> abf, 8 el/thread.
// blocks [5120,7168): out = bias broadcast (ONLY launched in atomic path).
__global__ __launch_bounds__(256) void prep_kernel(
    const float* __restrict__ x, const float* __restrict__ w,
    const float* __restrict__ bias, unsigned short* __restrict__ abf,
    unsigned short* __restrict__ bt, float* __restrict__ out) {
  const int bid = blockIdx.x;
  const int t = threadIdx.x;
  if (bid < 4096) {
    __shared__ __align__(16) unsigned short lT[8][512];  // [k][j'*8+p], 8KB
    const int i = bid >> 3;
    const int jg = bid & 7;
    const float4* src =
        (const float4*)(w + (size_t)i * 32768 + jg * 4096 + t * 16);
    float4 v0 = src[0], v1 = src[1], v2 = src[2], v3 = src[3];
    const int jp = (t >> 2) * 8 + (t & 3) * 2;  // j'*8 + p0 (even)
    const float* lo = (const float*)&v0;  // k=0..3, p0   (v1: k=4..7)
    const float* hi = (const float*)&v2;  // k=0..3, p0+1 (v3: k=4..7)
#pragma unroll
    for (int k = 0; k < 4; ++k) {
      unsigned int pk =
          (unsigned int)f2bf(lo[k]) | ((unsigned int)f2bf(hi[k]) << 16);
      *(unsigned int*)&lT[k][jp] = pk;
    }
    lo = (const float*)&v1;
    hi = (const float*)&v3;
#pragma unroll
    for (int k = 0; k < 4; ++k) {
      unsigned int pk =
          (unsigned int)f2bf(lo[k]) | ((unsigned int)f2bf(hi[k]) << 16);
      *(unsigned int*)&lT[k + 4][jp] = pk;
    }
    __syncthreads();
    const int r = t >> 5, c = t & 31;  // 32B/thread, 1KB contiguous runs
    const uint4* s = (const uint4*)&lT[r][c * 16];
    uint4* d = (uint4*)(bt + (size_t)(i * 8 + r) * K_DIM + jg * 512 + c * 16);
    d[0] = s[0];
    d[1] = s[1];
  } else if (bid < 5120) {
    int g = (bid - 4096) * 256 + t;  // [0, 262144); 8 elements each
    const float4* xi = (const float4*)x;
    float4 a = xi[g * 2];
    float4 b = xi[g * 2 + 1];
    __attribute__((aligned(16))) unsigned short o[8] = {
        f2bf(a.x), f2bf(a.y), f2bf(a.z), f2bf(a.w),
        f2bf(b.x), f2bf(b.y), f2bf(b.z), f2bf(b.w)};
    *(uint4*)(abf + (size_t)g * 8) = *(const uint4*)o;
  } else {
    int g = (bid - 5120) * 256 + t;  // [0, 524288); 4 elements each
    int el = g * 4;
    int col = el & (N_DIM - 1);
    *(float4*)(out + el) = *(const float4*)(bias + col);
  }
}

__device__ inline void gld16(const void* g, void* l) {
  __builtin_amdgcn_global_load_lds(
      (const __attribute__((address_space(1))) unsigned int*)g,
      (__attribute__((address_space(3))) unsigned int*)l, 16, 0, 0);
}

// Tile 128M x 128N, BK=32, 512 threads = 8 waves, wave-tile 64M x 32N (4x2).
// LDS: A 128x32 (8KB) + B 128x32 (8KB) per buffer, dbuf = 32KB.
__global__ __launch_bounds__(512, 4) void gemm_kernel(
    const unsigned short* __restrict__ A, const unsigned short* __restrict__ Bt,
    float* __restrict__ out, float* __restrict__ part, int use_atomic) {
  __shared__ __align__(16) char lds[2][16 * 1024];
  const int t = threadIdx.x;
  const int n0 = blockIdx.x * 128;
  const int m0 = blockIdx.y * 128;
  const int z = blockIdx.z;
  const int kc0 = z * (K_DIM / KSPLIT);
  const int w = t >> 6;
  const int lane = t & 63;
  const int wr = w >> 2;     // 0..1 -> 64 M-rows
  const int wc = w & 3;      // 0..3 -> 32 N-cols
  const int lrow = lane & 15;
  const int kb = lane >> 4;  // k-block 0..3 (8 bf16 each)

  f32x4 acc[4][2] = {};

  // staging: each thread 1 A-seg + 1 B-seg of 16B: row t>>2, col (t&3)*8.
  // LDS dest = wave-uniform base (w*1024) + lane*16 == lds + t*16.
  const size_t aOff = (size_t)(m0 + (t >> 2)) * K_DIM + kc0 + (t & 3) * 8;
  const size_t bOff = (size_t)(n0 + (t >> 2)) * K_DIM + kc0 + (t & 3) * 8;

  auto issue = [&](int it) {
    char* buf = lds[it & 1];
    gld16(A + aOff + it * 32, buf + t * 16);
    gld16(Bt + bOff + it * 32, buf + 8192 + t * 16);
  };

  issue(0);
  for (int it = 0; it < NIT; ++it) {
    __syncthreads();
    if (it + 1 < NIT) issue(it + 1);
    const unsigned short* cA = (const unsigned short*)lds[it & 1];
    const unsigned short* cB = cA + 4096;  // +8KB

    bf16x8 af[4], bfr[2];
#pragma unroll
    for (int mt = 0; mt < 4; ++mt)
      af[mt] = *(const bf16x8*)(cA + (wr * 64 + mt * 16 + lrow) * 32 + kb * 8);
#pragma unroll
    for (int nt = 0; nt < 2; ++nt)
      bfr[nt] = *(const bf16x8*)(cB + (wc * 32 + nt * 16 + lrow) * 32 + kb * 8);
#pragma unroll
    for (int mt = 0; mt < 4; ++mt)
#pragma unroll
      for (int nt = 0; nt < 2; ++nt)
        acc[mt][nt] = __builtin_amdgcn_mfma_f32_16x16x32_bf16(
            af[mt], bfr[nt], acc[mt][nt], 0, 0, 0);
  }

  // C/D layout (verified m89/m91): col = lane&15, row = (lane>>4)*4 + reg
#pragma unroll
  for (int mt = 0; mt < 4; ++mt) {
    const int gmb = m0 + wr * 64 + mt * 16 + kb * 4;
#pragma unroll
    for (int nt = 0; nt < 2; ++nt) {
      const int gn = n0 + wc * 32 + nt * 16 + lrow;
      if (use_atomic) {
#pragma unroll
        for (int r = 0; r < 4; ++r)
          atomicAdd(out + (size_t)(gmb + r) * N_DIM + gn, acc[mt][nt][r]);
      } else {
        float* p = part + (size_t)z * PART_ELEMS;
#pragma unroll
        for (int r = 0; r < 4; ++r)
          p[(size_t)(gmb + r) * N_DIM + gn] = acc[mt][nt][r];
      }
    }
  }
}

// out = sum_z part[z] + bias ; 2048 blocks x 256 thr x 1 float4
__global__ __launch_bounds__(256) void reduce_kernel(
    const float* __restrict__ part, const float* __restrict__ bias,
    float* __restrict__ out) {
  const int g = blockIdx.x * 256 + threadIdx.x;  // [0, 524288)
  const float4* p = (const float4*)part;
  const float4* b4 = (const float4*)bias;
  const int Q = PART_ELEMS / 4;  // 524288
  float4 s0 = p[g];
  float4 s1 = p[g + Q];
  float4 s2 = p[g + 2 * Q];
  float4 s3 = p[g + 3 * Q];
  float4 bb = b4[g & (N_DIM / 4 - 1)];
  float4 r;
  r.x = s0.x + s1.x + s2.x + s3.x + bb.x;
  r.y = s0.y + s1.y + s2.y + s3.y + bb.y;
  r.z = s0.z + s1.z + s2.z + s3.z + bb.z;
  r.w = s0.w + s1.w + s2.w + s3.w + bb.w;
  ((float4*)out)[g] = r;
}

extern "C" void kernel_launch(void* const* d_in, const int* in_sizes, int n_in,
                              void* d_out, int out_size, void* d_ws,
                              size_t ws_size, hipStream_t stream) {
  const float* x = (const float*)d_in[0];     // [512, 4096]
  const float* w = (const float*)d_in[1];     // [512, 512, 8, 8]
  const float* bias = (const float*)d_in[2];  // [512, 8]
  float* out = (float*)d_out;                 // [512, 4096]

  unsigned short* abf = (unsigned short*)d_ws;       // [0, 4MB) bf16 A
  unsigned short* bt = abf + (size_t)M_DIM * K_DIM;  // [4MB, 36MB) bf16 B^T
  float* part = (float*)((char*)d_ws + 36u * 1024 * 1024);  // [36MB, 68MB)

  const bool have_ws = ws_size >= 68ull * 1024 * 1024;
  const int use_atomic = have_ws ? 0 : 1;

  // bias-init segment only needed for the atomic path
  prep_kernel<<<use_atomic ? 7168 : 5120, 256, 0, stream>>>(x, w, bias, abf,
                                                            bt, out);

  dim3 grid(N_DIM / 128, M_DIM / 128, KSPLIT);  // 32 x 4 x 4 = 512 blocks
  gemm_kernel<<<grid, 512, 0, stream>>>(abf, bt, out, part, use_atomic);

  if (!use_atomic)
    reduce_kernel<<<PART_ELEMS / 4 / 256, 256, 0, stream>>>(part, bias, out);
}